// Round 1
// baseline (753.464 us; speedup 1.0000x reference)
//
#include <hip/hip_runtime.h>

#define SIZE_N 1024
#define DDIM   65536
#define D_TILE 64
#define S_CHUNK 64
#define NCHUNK (SIZE_N / S_CHUNK)   // 16
#define PITCH  65                   // 64 + 1 pad -> 2-way LDS bank aliasing (free)

// Double-buffered transpose tile: 2 x 64x65 floats = 33.3 KB -> 4 blocks/CU fits 160 KB LDS.
__global__ __launch_bounds__(256, 4) void reghd_main(
    const float* __restrict__ x,
    const float* __restrict__ w,
    const float* __restrict__ bias,
    const float* __restrict__ alpha,
    const float* __restrict__ M,
    float* __restrict__ out)
{
    __shared__ float tile[2][S_CHUNK * PITCH];

    const int t      = threadIdx.x;
    const int lane16 = t & 15;          // s-quad index within row group
    const int grp    = t >> 4;          // 0..15 row group
    const int d0     = blockIdx.x * D_TILE;
    const int sx     = lane16 * 4;

    float* __restrict__ hvs = out + 1 + DDIM;   // hvs[s*DDIM + d]

    // Phase-B decomposition: idx = t + 256*p2 -> srow = (t>>6) + 4*p2, dl = t&63 (constant)
    const int srow0 = t >> 6;
    const int dl    = t & 63;

    float acc[4] = {0.f, 0.f, 0.f, 0.f};        // alpha-weighted row sums, rows grp+16p

    // ---- prologue: chunk 0 operands into registers ----
    float4 x4 = *reinterpret_cast<const float4*>(x + sx);
    float4 a4 = *reinterpret_cast<const float4*>(alpha + sx);
    float4 w4[4], b4[4];
    #pragma unroll
    for (int p = 0; p < 4; ++p) {
        const size_t base = (size_t)(d0 + grp + 16 * p) * SIZE_N + sx;
        w4[p] = *reinterpret_cast<const float4*>(w + base);
        b4[p] = *reinterpret_cast<const float4*>(bias + base);
    }

    #pragma unroll 2
    for (int c = 0; c < NCHUNK; ++c) {
        const int s0 = c * S_CHUNK;
        float* __restrict__ buf = tile[c & 1];

        // ---- prefetch chunk c+1 (clamped at the tail: redundant L2-hit reload) ----
        // Issued BEFORE the trig so ~900cy HBM latency hides under ~1000cy of VALU.
        const int s1 = (c + 1 < NCHUNK) ? (s0 + S_CHUNK) : s0;
        float4 x4n = *reinterpret_cast<const float4*>(x + s1 + sx);
        float4 a4n = *reinterpret_cast<const float4*>(alpha + s1 + sx);
        float4 w4n[4], b4n[4];
        #pragma unroll
        for (int p = 0; p < 4; ++p) {
            const size_t base = (size_t)(d0 + grp + 16 * p) * SIZE_N + s1 + sx;
            w4n[p] = *reinterpret_cast<const float4*>(w + base);
            b4n[p] = *reinterpret_cast<const float4*>(bias + base);
        }

        // ---- Phase A: trig + LDS transpose + alpha-weighted row sums ----
        #pragma unroll
        for (int p = 0; p < 4; ++p) {
            const int row = grp + 16 * p;               // 0..63
            const float p0 = x4.x * w4[p].x;
            const float p1 = x4.y * w4[p].y;
            const float p2 = x4.z * w4[p].z;
            const float p3 = x4.w * w4[p].w;
            const float e0 = cosf(p0 + b4[p].x) * sinf(p0);
            const float e1 = cosf(p1 + b4[p].y) * sinf(p1);
            const float e2 = cosf(p2 + b4[p].z) * sinf(p2);
            const float e3 = cosf(p3 + b4[p].w) * sinf(p3);

            buf[(sx + 0) * PITCH + row] = e0;
            buf[(sx + 1) * PITCH + row] = e1;
            buf[(sx + 2) * PITCH + row] = e2;
            buf[(sx + 3) * PITCH + row] = e3;

            acc[p] += e0 * a4.x + e1 * a4.y + e2 * a4.z + e3 * a4.w;
        }

        // Make LDS writes visible, then raw barrier. Deliberately NO vmcnt drain:
        // the chunk-(c+1) prefetch loads and chunk-(c-?) nt stores stay in flight.
        // (hipcc's __syncthreads would emit s_waitcnt vmcnt(0) here — the m97 stall.)
        asm volatile("s_waitcnt lgkmcnt(0)" ::: "memory");
        __builtin_amdgcn_s_barrier();
        asm volatile("" ::: "memory");

        // ---- Phase B: coalesced transposed writes. 64 consecutive d per wave-store.
        // Nontemporal: hvs is never re-read; keeps w/bias resident in L3 across calls.
        {
            const float* lsrc = buf + srow0 * PITCH + dl;
            float*       gdst = hvs + (size_t)(s0 + srow0) * DDIM + d0 + dl;
            #pragma unroll
            for (int p2 = 0; p2 < 16; ++p2) {
                __builtin_nontemporal_store(lsrc[p2 * 4 * PITCH], gdst);
                gdst += (size_t)4 * DDIM;
            }
        }

        // Rotate pipeline registers. Safe buffer reuse at distance 2: a thread only
        // reaches A(c+2) [writes buf c&1] after barrier(c+1), which every thread
        // reaches only after finishing its B(c) reads of buf c&1.
        x4 = x4n; a4 = a4n;
        #pragma unroll
        for (int p = 0; p < 4; ++p) { w4[p] = w4n[p]; b4[p] = b4n[p]; }
    }

    // ---- epilogue: bundled -> q, partial model_result = dot(q, M) for this tile ----
    float local_dot = 0.f;
    #pragma unroll
    for (int p = 0; p < 4; ++p) {
        float s = acc[p];
        #pragma unroll
        for (int m = 1; m < 16; m <<= 1) s += __shfl_xor(s, m);
        if (lane16 == 0) {
            const int d = d0 + grp + 16 * p;
            const float qv = (s > 0.f) ? 1.f : -1.f;
            out[1 + d] = qv;
            local_dot += qv * M[d];
        }
    }
    // lanes 0,16,32,48 hold partials; fold to lane 0, one atomic per wave
    local_dot += __shfl_xor(local_dot, 16);
    local_dot += __shfl_xor(local_dot, 32);
    if ((t & 63) == 0) atomicAdd(out, local_dot);
}

extern "C" void kernel_launch(void* const* d_in, const int* in_sizes, int n_in,
                              void* d_out, int out_size, void* d_ws, size_t ws_size,
                              hipStream_t stream) {
    const float* x     = (const float*)d_in[0];
    const float* w     = (const float*)d_in[1];
    const float* bias  = (const float*)d_in[2];
    const float* alpha = (const float*)d_in[3];
    const float* M     = (const float*)d_in[4];
    float* out = (float*)d_out;

    // out[0] accumulates model_result via atomics; harness poisons d_out each call
    hipMemsetAsync(out, 0, sizeof(float), stream);

    reghd_main<<<dim3(DDIM / D_TILE), dim3(256), 0, stream>>>(x, w, bias, alpha, M, out);
}

// Round 2
// 725.766 us; speedup vs baseline: 1.0382x; 1.0382x over previous
//
#include <hip/hip_runtime.h>

#define SIZE_N 1024
#define DDIM   65536
#define D_TILE 64
#define S_CHUNK 64
#define NCHUNK (SIZE_N / S_CHUNK)   // 16
#define PITCH  65                   // 64 + 1 pad -> <=2-way LDS bank aliasing (free)

// Hardware trig: v_sin_f32/v_cos_f32 compute sin/cos(2*pi*r). Reduce with v_fract
// (valid for negatives: fract(x) = x - floor(x) in [0,1)). ~3 VALU ops vs ~30 for OCML.
__device__ __forceinline__ float sin2pi(float r) {
    return __builtin_amdgcn_sinf(__builtin_amdgcn_fractf(r));
}
__device__ __forceinline__ float cos2pi(float r) {
    return __builtin_amdgcn_cosf(__builtin_amdgcn_fractf(r));
}

#define INV2PI 0.15915494309189535f

// tile[s_local * PITCH + d_local], 64x65 floats = 16.6 KB
__global__ __launch_bounds__(256, 4) void reghd_main(
    const float* __restrict__ x,
    const float* __restrict__ w,
    const float* __restrict__ bias,
    const float* __restrict__ alpha,
    const float* __restrict__ M,
    float* __restrict__ out)
{
    __shared__ float tile[S_CHUNK * PITCH];

    const int t      = threadIdx.x;
    const int lane16 = t & 15;          // s-quad index within row group
    const int grp    = t >> 4;          // 0..15 row group
    const int d0     = blockIdx.x * D_TILE;

    float* __restrict__ hvs = out + 1 + DDIM;   // hvs[s*DDIM + d]

    float acc[4] = {0.f, 0.f, 0.f, 0.f};        // row sums for rows grp+16p

    for (int c = 0; c < NCHUNK; ++c) {
        const int s0 = c * S_CHUNK;
        const int sx = lane16 * 4;

        // x/alpha quads: 16B aligned (s0+sx multiple of 4), L1-resident after first chunk
        const float4 x4 = *reinterpret_cast<const float4*>(x + s0 + sx);
        const float4 a4 = *reinterpret_cast<const float4*>(alpha + s0 + sx);

        // pre-scale x into revolutions: r = (x/2pi)*w, r+b/2pi for the cos arg
        const float xr0 = x4.x * INV2PI;
        const float xr1 = x4.y * INV2PI;
        const float xr2 = x4.z * INV2PI;
        const float xr3 = x4.w * INV2PI;

        #pragma unroll
        for (int p = 0; p < 4; ++p) {
            const int row = grp + 16 * p;               // 0..63
            const size_t base = (size_t)(d0 + row) * SIZE_N + s0 + sx;
            const float4 w4 = *reinterpret_cast<const float4*>(w + base);
            const float4 b4 = *reinterpret_cast<const float4*>(bias + base);

            // rN = p/2pi ; rbN = (p+b)/2pi
            const float r0 = xr0 * w4.x;
            const float r1 = xr1 * w4.y;
            const float r2 = xr2 * w4.z;
            const float r3 = xr3 * w4.w;
            const float rb0 = fmaf(b4.x, INV2PI, r0);
            const float rb1 = fmaf(b4.y, INV2PI, r1);
            const float rb2 = fmaf(b4.z, INV2PI, r2);
            const float rb3 = fmaf(b4.w, INV2PI, r3);

            const float e0 = cos2pi(rb0) * sin2pi(r0);
            const float e1 = cos2pi(rb1) * sin2pi(r1);
            const float e2 = cos2pi(rb2) * sin2pi(r2);
            const float e3 = cos2pi(rb3) * sin2pi(r3);

            // transpose into LDS: tile[s][d]
            tile[(sx + 0) * PITCH + row] = e0;
            tile[(sx + 1) * PITCH + row] = e1;
            tile[(sx + 2) * PITCH + row] = e2;
            tile[(sx + 3) * PITCH + row] = e3;

            acc[p] += e0 * a4.x + e1 * a4.y + e2 * a4.z + e3 * a4.w;
        }
        __syncthreads();

        // Phase B: coalesced transposed write. Each wave instr: 64 consecutive d
        // (256 B contiguous).
        #pragma unroll
        for (int p2 = 0; p2 < 16; ++p2) {
            const int idx  = t + 256 * p2;
            const int srow = idx >> 6;      // uniform per wave
            const int dl   = idx & 63;      // = lane
            const float v  = tile[srow * PITCH + dl];
            hvs[(size_t)(s0 + srow) * DDIM + d0 + dl] = v;
        }
        __syncthreads();
    }

    // bundled -> q, and partial model_result = dot(q, M) for this tile
    float local_dot = 0.f;
    #pragma unroll
    for (int p = 0; p < 4; ++p) {
        float s = acc[p];
        #pragma unroll
        for (int m = 1; m < 16; m <<= 1) s += __shfl_xor(s, m);
        if (lane16 == 0) {
            const int d = d0 + grp + 16 * p;
            const float qv = (s > 0.f) ? 1.f : -1.f;
            out[1 + d] = qv;
            local_dot += qv * M[d];
        }
    }
    // lanes 0,16,32,48 hold partials; fold to lane 0, one atomic per wave
    local_dot += __shfl_xor(local_dot, 16);
    local_dot += __shfl_xor(local_dot, 32);
    if ((t & 63) == 0) atomicAdd(out, local_dot);
}

extern "C" void kernel_launch(void* const* d_in, const int* in_sizes, int n_in,
                              void* d_out, int out_size, void* d_ws, size_t ws_size,
                              hipStream_t stream) {
    const float* x     = (const float*)d_in[0];
    const float* w     = (const float*)d_in[1];
    const float* bias  = (const float*)d_in[2];
    const float* alpha = (const float*)d_in[3];
    const float* M     = (const float*)d_in[4];
    float* out = (float*)d_out;

    // out[0] accumulates model_result via atomics; harness poisons d_out each call
    hipMemsetAsync(out, 0, sizeof(float), stream);

    reghd_main<<<dim3(DDIM / D_TILE), dim3(256), 0, stream>>>(x, w, bias, alpha, M, out);
}